// Round 18
// baseline (182.726 us; speedup 1.0000x reference)
//
#include <hip/hip_runtime.h>
#include <hip/hip_fp16.h>
#include <math.h>

#define F_IN 128
constexpr int SB = 256;
constexpr float LOG2E = 1.4426950408889634f;
constexpr int CAP = 131072;   // per-bucket edge capacity
constexpr int CHUNK = 2048;   // edges per bucketing block
constexpr int NPAD = 50176;   // per-replica deg stride (>= N+1, 256B-aligned)

// scan1: exclusive scan input = sum of 8 XCD-local deg replicas (+1 self-loop)
__global__ void scan1(const int* __restrict__ degr, int* __restrict__ out,
                      int* __restrict__ bsums, int n, int selfN) {
    __shared__ int sm[SB];
    int i = blockIdx.x * SB + threadIdx.x;
    int v = 0;
    if (i < n) {
#pragma unroll
        for (int r = 0; r < 8; ++r) v += degr[r * NPAD + i];
        if (i < selfN) v += 1;
    }
    sm[threadIdx.x] = v;
    __syncthreads();
    for (int d = 1; d < SB; d <<= 1) {
        int t = (threadIdx.x >= d) ? sm[threadIdx.x - d] : 0;
        __syncthreads();
        sm[threadIdx.x] += t;
        __syncthreads();
    }
    if (i < n) out[i] = sm[threadIdx.x] - v;
    if (threadIdx.x == SB - 1) bsums[blockIdx.x] = sm[SB - 1];
}

__global__ void scan2(int* __restrict__ bsums, int nb) {
    __shared__ int sm[SB];
    int v = (threadIdx.x < nb) ? bsums[threadIdx.x] : 0;
    sm[threadIdx.x] = v;
    __syncthreads();
    for (int d = 1; d < SB; d <<= 1) {
        int t = (threadIdx.x >= d) ? sm[threadIdx.x - d] : 0;
        __syncthreads();
        sm[threadIdx.x] += t;
        __syncthreads();
    }
    if (threadIdx.x < nb) bsums[threadIdx.x] = sm[threadIdx.x] - v;
}

__global__ void scan3(int* __restrict__ off, int* __restrict__ cursor,
                      const int* __restrict__ bsums, int n, int ncur) {
    int i = blockIdx.x * SB + threadIdx.x;
    if (i < n) {
        int v = off[i] + bsums[blockIdx.x];
        off[i] = v;
        if (i < ncur) cursor[i] = v;
    }
}

// GEMM body; A float or __half; smem passed in. Bank-conflict-free column
// chunks {tx*4, 64+tx*4}; fp16 C; fp32 logit epilogue PRE-SCALED by log2e.
template <int BN, int TN, int HEADS, typename AT>
__device__ __forceinline__ void gemm_dev(
    const AT* __restrict__ A, const float* __restrict__ B,
    const float* __restrict__ asrc, const float* __restrict__ adst,
    __half* __restrict__ C, float* __restrict__ als, float* __restrict__ ald,
    int M, int bid, char* smem) {
    constexpr int BM = 128, BK = 16, TM = 4, K = 128;
    float (*As)[BM + 4] = (float (*)[BM + 4])smem;
    float (*Bs)[BN] = (float (*)[BN])(smem + (size_t)BK * (BM + 4) * 4);
    const int tx = threadIdx.x, ty = threadIdx.y;
    const int tid = ty * 16 + tx;
    const int row0 = bid * BM;
    const int i0 = ty * TM;
    const int j0a = tx * 4;
    const int j0b = 64 + tx * 4;

    float acc[TM][TN];
#pragma unroll
    for (int m = 0; m < TM; ++m)
#pragma unroll
        for (int n = 0; n < TN; ++n) acc[m][n] = 0.f;

    const int ar = tid >> 2;
    const int ak = (tid & 3) * 4;
    int arow = row0 + ar;
    if (arow >= M) arow = M - 1;
    const AT* Aptr = A + (size_t)arow * K + ak;
    const int bk = (BN == 128) ? (tid >> 5) : (tid >> 4);
    const int bc = (BN == 128) ? ((tid & 31) * 4) : ((tid & 15) * 4);
    const bool bact = (BN == 128) || (tid < 256);

    for (int kc = 0; kc < K; kc += BK) {
        float a0, a1v, a2v, a3v;
        if constexpr (sizeof(AT) == 4) {
            float4 av = *(const float4*)(Aptr + kc);
            a0 = av.x; a1v = av.y; a2v = av.z; a3v = av.w;
        } else {
            uint2 raw = *(const uint2*)(Aptr + kc);
            __half2 h01 = *(__half2*)&raw.x;
            __half2 h23 = *(__half2*)&raw.y;
            float2 f01 = __half22float2(h01);
            float2 f23 = __half22float2(h23);
            a0 = f01.x; a1v = f01.y; a2v = f23.x; a3v = f23.y;
        }
        float4 bv;
        if (bact) bv = *(const float4*)(B + (size_t)(kc + bk) * BN + bc);
        __syncthreads();
        As[ak + 0][ar] = a0;
        As[ak + 1][ar] = a1v;
        As[ak + 2][ar] = a2v;
        As[ak + 3][ar] = a3v;
        if (bact) *(float4*)&Bs[bk][bc] = bv;
        __syncthreads();
#pragma unroll
        for (int kk = 0; kk < BK; ++kk) {
            float4 a4 = *(const float4*)&As[kk][i0];
            float arr[TM] = {a4.x, a4.y, a4.z, a4.w};
            float br[TN];
            float4 b0 = *(const float4*)&Bs[kk][j0a];
            br[0] = b0.x; br[1] = b0.y; br[2] = b0.z; br[3] = b0.w;
            if constexpr (TN == 8) {
                float4 b1 = *(const float4*)&Bs[kk][j0b];
                br[4] = b1.x; br[5] = b1.y; br[6] = b1.z; br[7] = b1.w;
            }
#pragma unroll
            for (int m = 0; m < TM; ++m)
#pragma unroll
                for (int n = 0; n < TN; ++n) acc[m][n] += arr[m] * br[n];
        }
    }

#pragma unroll
    for (int m = 0; m < TM; ++m) {
        int row = row0 + i0 + m;
        bool ok = row < M;
        if constexpr (TN == 8) {
            if (ok) {
                alignas(8) __half2 pa[2], pb[2];
#pragma unroll
                for (int n2 = 0; n2 < 2; ++n2) {
                    pa[n2] = __floats2half2_rn(acc[m][2 * n2], acc[m][2 * n2 + 1]);
                    pb[n2] = __floats2half2_rn(acc[m][4 + 2 * n2], acc[m][5 + 2 * n2]);
                }
                *(uint2*)&C[(size_t)row * BN + j0a] = *(uint2*)pa;
                *(uint2*)&C[(size_t)row * BN + j0b] = *(uint2*)pb;
            }
            float psA = 0.f, pdA = 0.f, psB = 0.f, pdB = 0.f;
#pragma unroll
            for (int n = 0; n < 4; ++n) {
                psA += acc[m][n] * asrc[j0a + n];
                pdA += acc[m][n] * adst[j0a + n];
                psB += acc[m][n + 4] * asrc[j0b + n];
                pdB += acc[m][n + 4] * adst[j0b + n];
            }
#pragma unroll
            for (int msk = 1; msk < 8; msk <<= 1) {
                psA += __shfl_xor(psA, msk, 64);
                pdA += __shfl_xor(pdA, msk, 64);
                psB += __shfl_xor(psB, msk, 64);
                pdB += __shfl_xor(pdB, msk, 64);
            }
            if (ok && (tx & 7) == 0) {
                int hA = tx >> 3;
                als[row * HEADS + hA] = psA * LOG2E;
                ald[row * HEADS + hA] = pdA * LOG2E;
                als[row * HEADS + 2 + hA] = psB * LOG2E;
                ald[row * HEADS + 2 + hA] = pdB * LOG2E;
            }
        } else {
            if (ok) {
                alignas(8) __half2 ph[2];
#pragma unroll
                for (int n2 = 0; n2 < 2; ++n2)
                    ph[n2] = __floats2half2_rn(acc[m][2 * n2], acc[m][2 * n2 + 1]);
                *(uint2*)&C[(size_t)row * BN + j0a] = *(uint2*)ph;
            }
            float ps = 0.f, pd = 0.f;
#pragma unroll
            for (int n = 0; n < TN; ++n) {
                ps += acc[m][n] * asrc[j0a + n];
                pd += acc[m][n] * adst[j0a + n];
            }
#pragma unroll
            for (int msk = 1; msk < 8; msk <<= 1) {
                ps += __shfl_xor(ps, msk, 64);
                pd += __shfl_xor(pd, msk, 64);
            }
            if (ok && (tx & 7) == 0) {
                int h0 = tx >> 3;
                als[row * HEADS + h0] = ps * LOG2E;
                ald[row * HEADS + h0] = pd * LOG2E;
            }
        }
    }
}

// Mega-kernel: blocks [0,gblk) = layer-1 GEMM. Blocks [gblk,...) = bucketing
// with BALLOT-based slot assignment: 8 ballots/batch give per-lane ranks;
// only lane 0 touches the LDS histogram (1 atomic per wave-bucket) -> no
// 256-way same-address LDS atomic serialization.
__global__ __launch_bounds__(512) void gemm1_bucket(
    const float* __restrict__ A, const float* __restrict__ B,
    const float* __restrict__ asrc, const float* __restrict__ adst,
    __half* __restrict__ C, float* __restrict__ als, float* __restrict__ ald,
    int M, int gblk,
    const int* __restrict__ src, const int* __restrict__ dst,
    int* __restrict__ degr, int* __restrict__ bucketcur,
    int2* __restrict__ ebuf, int E, int nspan, int nchunk) {
    __shared__ __align__(16) char smem[CHUNK * 8 + 32 * 4];
    if ((int)blockIdx.x < gblk) {
        gemm_dev<128, 8, 4, float>(A, B, asrc, adst, C, als, ald, M, blockIdx.x, smem);
        return;
    }
    int cid = blockIdx.x - gblk;
    if (cid >= nchunk) return;
    int tid = threadIdx.y * 16 + threadIdx.x;  // 0..511
    int lane = tid & 63;
    unsigned long long below = (lane == 63) ? ~0ull >> 1 : (1ull << lane) - 1;
    int* degrep = degr + (blockIdx.x & 7) * NPAD;
    int2* stage = (int2*)smem;
    int* hist = (int*)(smem + CHUNK * 8);
    int* bbase = hist + 8;
    int* gbase = hist + 16;
    if (tid < 8) hist[tid] = 0;
    __syncthreads();
    int ebase = cid * CHUNK;
    int s[4], d[4], bk[4], slot[4];
#pragma unroll
    for (int k = 0; k < 4; ++k) {
        int e = ebase + k * 512 + tid;
        bool v = e < E;
        s[k] = v ? src[e] : 0;
        d[k] = v ? dst[e] : 0;
        bk[k] = v ? d[k] / nspan : -1;
        if (v) atomicAdd(&degrep[d[k]], 1);           // XCD-local replica
        // ballot-based within-wave rank + single LDS atomic per wave-bucket
#pragma unroll
        for (int bb = 0; bb < 8; ++bb) {
            unsigned long long msk = __ballot(bk[k] == bb);
            int cnt = __popcll(msk);
            int base = 0;
            if (cnt) {
                if (lane == 0) base = atomicAdd(&hist[bb], cnt);
                base = __shfl(base, 0, 64);
            }
            if (bk[k] == bb) slot[k] = base + __popcll(msk & below);
        }
    }
    __syncthreads();
    if (tid == 0) {
        int run = 0;
#pragma unroll
        for (int b = 0; b < 8; ++b) { bbase[b] = run; run += hist[b]; }
    }
    if (tid < 8) gbase[tid] = atomicAdd(&bucketcur[tid], hist[tid]);
    __syncthreads();
#pragma unroll
    for (int k = 0; k < 4; ++k)
        if (bk[k] >= 0) stage[bbase[bk[k]] + slot[k]] = make_int2(s[k], d[k]);
    __syncthreads();
    for (int b = 0; b < 8; ++b) {
        int c0 = bbase[b], cN = hist[b];
        size_t g0 = (size_t)b * CAP + gbase[b];
        for (int j = tid; j < cN; j += 512) ebuf[g0 + j] = stage[c0 + j];
    }
}

// Pass B: partition g (= blockIdx&7, XCD-aligned) reads its bucket
// sequentially, scatters src (ushort) into its L2-resident csr slice.
__global__ void scatter_b(const int2* __restrict__ ebuf,
                          const int* __restrict__ bucketcur,
                          int* __restrict__ cursor, unsigned short* __restrict__ csr,
                          int N, int nspan, int spb) {
    int g = blockIdx.x & 7;
    int c = blockIdx.x >> 3;
    int tid = threadIdx.x;
    int cnt = bucketcur[g];
    const int2* eb = ebuf + (size_t)g * CAP;
    int stride = spb * 256;
    for (int i = c * 256 + tid; i < cnt; i += stride) {
        int2 e = eb[i];
        int p = atomicAdd(&cursor[e.y], 1);
        csr[p] = (unsigned short)e.x;
    }
    int r0 = g * nspan, r1 = r0 + nspan;
    if (r1 > N) r1 = N;
    for (int i = r0 + c * 256 + tid; i < r1; i += stride) {
        int p = atomicAdd(&cursor[i], 1);
        csr[p] = (unsigned short)i;
    }
}

// Layer-2 GEMM (standalone, fp16 A)
template <int BN, int TN, int HEADS>
__global__ __launch_bounds__(512) void gemm_fused_h(
    const __half* __restrict__ A, const float* __restrict__ B,
    const float* __restrict__ asrc, const float* __restrict__ adst,
    __half* __restrict__ C, float* __restrict__ als, float* __restrict__ ald,
    int M) {
    __shared__ __align__(16) char smem[16 * 132 * 4 + 16 * BN * 4];
    gemm_dev<BN, TN, HEADS, __half>(A, B, asrc, adst, C, als, ald, M, blockIdx.x, smem);
}

// Layer-1 aggregation, edge-group layout: wave = 1 node; 4 groups x 16 lanes.
__global__ void gat_agg_l1(const __half* __restrict__ h,
                           const float* __restrict__ als, const float* __restrict__ ald,
                           const float* __restrict__ bias,
                           const int* __restrict__ off,
                           const unsigned short* __restrict__ csr,
                           __half* __restrict__ out, int n) {
    int wid = (blockIdx.x * blockDim.x + threadIdx.x) >> 6;
    int lane = threadIdx.x & 63;
    if (wid >= n) return;
    const int g = lane >> 4;
    const int q = lane & 15;
    const int hd = q >> 2;
    float ad = ald[wid * 4 + hd];
    int e0 = off[wid], e1 = off[wid + 1];
    const __half* hq = h + q * 8;

    float acc[8] = {0.f, 0.f, 0.f, 0.f, 0.f, 0.f, 0.f, 0.f};
    float D = 0.f;

    auto LD = [&](int ebase, uint4& h4, float& al) {
        int ee = ebase + g;
        int ie = (ee < e1) ? ee : e1 - 1;
        int s = csr[ie];
        float av = als[s * 4 + hd];
        al = (ee < e1) ? av : -1e30f;
        h4 = *(const uint4*)(hq + (size_t)s * 128);
    };
    auto PROC = [&](const uint4& h4, float al) {
        float lg = al + ad;
        lg = fmaxf(lg, 0.2f * lg);
        float exv = exp2f(lg);
        D += exv;
        const __half2* hh = (const __half2*)&h4;
#pragma unroll
        for (int i = 0; i < 4; ++i) {
            float2 f = __half22float2(hh[i]);
            acc[2 * i] = fmaf(exv, f.x, acc[2 * i]);
            acc[2 * i + 1] = fmaf(exv, f.y, acc[2 * i + 1]);
        }
    };

    uint4 hA, hB;
    float alA, alB;
    LD(e0, hA, alA);
    LD(e0 + 4, hB, alB);
    int e = e0;
    for (; e + 8 < e1; e += 8) {
        uint4 nA, nB;
        float nalA, nalB;
        LD(e + 8, nA, nalA);
        LD(e + 12, nB, nalB);
        PROC(hA, alA);
        PROC(hB, alB);
        hA = nA; alA = nalA;
        hB = nB; alB = nalB;
    }
    PROC(hA, alA);
    PROC(hB, alB);

#pragma unroll
    for (int i = 0; i < 8; ++i) {
        acc[i] += __shfl_xor(acc[i], 16, 64);
        acc[i] += __shfl_xor(acc[i], 32, 64);
    }
    D += __shfl_xor(D, 16, 64);
    D += __shfl_xor(D, 32, 64);

    if (g == 0) {
        float inv = 1.f / D;
        alignas(16) __half2 ph[4];
#pragma unroll
        for (int i = 0; i < 4; ++i) {
            float2 bv = ((const float2*)bias)[q * 4 + i];
            float vx = acc[2 * i] * inv + bv.x;
            float vy = acc[2 * i + 1] * inv + bv.y;
            vx = vx > 0.f ? vx : (__expf(vx) - 1.f);
            vy = vy > 0.f ? vy : (__expf(vy) - 1.f);
            ph[i] = __floats2half2_rn(vx, vy);
        }
        *(uint4*)(out + (size_t)wid * 128 + q * 8) = *(uint4*)ph;
    }
}

// Layer-2 aggregation (C=64): 8 groups x 8 lanes; fused layer-3 head.
__global__ void gat_agg_l2(const __half* __restrict__ h,
                           const float* __restrict__ als, const float* __restrict__ ald,
                           const float* __restrict__ bias,
                           const int* __restrict__ off,
                           const unsigned short* __restrict__ csr,
                           const float* __restrict__ W3, const float* __restrict__ as3,
                           const float* __restrict__ ad3, float2* __restrict__ hs,
                           float* __restrict__ ald3, int n) {
    int wid = (blockIdx.x * blockDim.x + threadIdx.x) >> 6;
    int lane = threadIdx.x & 63;
    if (wid >= n) return;
    const int g = lane >> 3;
    const int q = lane & 7;
    const int hd = q >> 2;
    float ad = ald[wid * 2 + hd];
    int e0 = off[wid], e1 = off[wid + 1];
    const __half* hq = h + q * 8;

    float acc[8] = {0.f, 0.f, 0.f, 0.f, 0.f, 0.f, 0.f, 0.f};
    float D = 0.f;

    auto LD = [&](int ebase, uint4& h4, float& al) {
        int ee = ebase + g;
        int ie = (ee < e1) ? ee : e1 - 1;
        int s = csr[ie];
        float av = als[s * 2 + hd];
        al = (ee < e1) ? av : -1e30f;
        h4 = *(const uint4*)(hq + (size_t)s * 64);
    };
    auto PROC = [&](const uint4& h4, float al) {
        float lg = al + ad;
        lg = fmaxf(lg, 0.2f * lg);
        float exv = exp2f(lg);
        D += exv;
        const __half2* hh = (const __half2*)&h4;
#pragma unroll
        for (int i = 0; i < 4; ++i) {
            float2 f = __half22float2(hh[i]);
            acc[2 * i] = fmaf(exv, f.x, acc[2 * i]);
            acc[2 * i + 1] = fmaf(exv, f.y, acc[2 * i + 1]);
        }
    };

    uint4 hA, hB;
    float alA, alB;
    LD(e0, hA, alA);
    LD(e0 + 8, hB, alB);
    int e = e0;
    for (; e + 16 < e1; e += 16) {
        uint4 nA, nB;
        float nalA, nalB;
        LD(e + 16, nA, nalA);
        LD(e + 24, nB, nalB);
        PROC(hA, alA);
        PROC(hB, alB);
        hA = nA; alA = nalA;
        hB = nB; alB = nalB;
    }
    PROC(hA, alA);
    PROC(hB, alB);

#pragma unroll
    for (int i = 0; i < 8; ++i) {
        acc[i] += __shfl_xor(acc[i], 8, 64);
        acc[i] += __shfl_xor(acc[i], 16, 64);
        acc[i] += __shfl_xor(acc[i], 32, 64);
    }
    D += __shfl_xor(D, 8, 64);
    D += __shfl_xor(D, 16, 64);
    D += __shfl_xor(D, 32, 64);

    float inv = 1.f / D;
    float r = 0.f;
#pragma unroll
    for (int i = 0; i < 8; ++i) {
        float v = acc[i] * inv + bias[q * 8 + i];
        v = v > 0.f ? v : (__expf(v) - 1.f);
        r = fmaf(v, W3[q * 8 + i], r);
    }
#pragma unroll
    for (int msk = 1; msk < 8; msk <<= 1) r += __shfl_xor(r, msk, 64);
    if (lane == 0) {
        hs[wid] = make_float2(r, r * as3[0] * LOG2E);
        ald3[wid] = r * ad3[0] * LOG2E;
    }
}

// Layer-3 aggregation: thread per node, 2-wide pipeline, packed 8B gather.
__global__ void gat_agg1(const float2* __restrict__ hs, const float* __restrict__ ald3,
                         const float* __restrict__ bias,
                         const int* __restrict__ off,
                         const unsigned short* __restrict__ csr,
                         float* __restrict__ out, int n) {
    int i = blockIdx.x * blockDim.x + threadIdx.x;
    if (i >= n) return;
    float ad = ald3[i];
    int e0 = off[i], e1 = off[i + 1];
    float S = 0.f, D = 0.f;
    float2 g[2];
    float valid[2];
#pragma unroll
    for (int p = 0; p < 2; ++p) {
        int ee = e0 + p;
        int ie = (ee < e1) ? ee : e1 - 1;
        int s = csr[ie];
        g[p] = hs[s];
        valid[p] = (ee < e1) ? 0.f : -1e30f;
    }
    int e = e0;
    for (; e + 2 < e1; e += 2) {
#pragma unroll
        for (int p = 0; p < 2; ++p) {
            int ee = e + 2 + p;
            int ie = (ee < e1) ? ee : e1 - 1;
            int s = csr[ie];
            float2 ng = hs[s];
            float nvalid = (ee < e1) ? 0.f : -1e30f;
            float lg = g[p].y + ad + valid[p];
            lg = fmaxf(lg, 0.2f * lg);
            float exv = exp2f(lg);
            D += exv;
            S = fmaf(exv, g[p].x, S);
            g[p] = ng;
            valid[p] = nvalid;
        }
    }
#pragma unroll
    for (int p = 0; p < 2; ++p) {
        float lg = g[p].y + ad + valid[p];
        lg = fmaxf(lg, 0.2f * lg);
        float exv = exp2f(lg);
        D += exv;
        S = fmaf(exv, g[p].x, S);
    }
    out[i] = S / D + bias[0];
}

extern "C" void kernel_launch(void* const* d_in, const int* in_sizes, int n_in,
                              void* d_out, int out_size, void* d_ws, size_t ws_size,
                              hipStream_t stream) {
    const float* x   = (const float*)d_in[0];
    const int*   ei  = (const int*)d_in[1];
    const float* W1  = (const float*)d_in[2];
    const float* as1 = (const float*)d_in[3];
    const float* ad1 = (const float*)d_in[4];
    const float* b1  = (const float*)d_in[5];
    const float* W2  = (const float*)d_in[6];
    const float* as2 = (const float*)d_in[7];
    const float* ad2 = (const float*)d_in[8];
    const float* b2  = (const float*)d_in[9];
    const float* W3  = (const float*)d_in[10];
    const float* as3 = (const float*)d_in[11];
    const float* ad3 = (const float*)d_in[12];
    const float* b3  = (const float*)d_in[13];
    float* out = (float*)d_out;

    const int N = in_sizes[0] / F_IN;  // 50000
    const int E = in_sizes[1] / 2;     // 800000
    const int ET = E + N;

    char* w = (char*)d_ws;
    size_t o = 0;
    auto alloc = [&](size_t bytes) -> void* {
        void* p = w + o;
        o += (bytes + 255) & ~(size_t)255;
        return p;
    };
    __half* hbuf = (__half*)alloc((size_t)N * 128 * 2);  // h1; reused as h2
    __half* a1   = (__half*)alloc((size_t)N * 128 * 2);
    float2* hs   = (float2*)alloc((size_t)N * 8);        // {h3, als3'}
    float* als  = (float*)alloc((size_t)N * 4 * 4);
    float* ald  = (float*)alloc((size_t)N * 4 * 4);
    float* ald3 = (float*)alloc((size_t)N * 4);
    int* degr   = (int*)alloc((size_t)8 * NPAD * 4);     // 8 XCD-local replicas
    int* bucketcur = (int*)alloc(8 * 4);
    int* off    = (int*)alloc((size_t)(N + 1) * 4);
    int* cursor = (int*)alloc((size_t)N * 4);
    int* bsums  = (int*)alloc(1024);
    unsigned short* csr = (unsigned short*)alloc((size_t)ET * 2);
    int2* ebuf  = (int2*)alloc((size_t)8 * CAP * 8);

    __half* h2 = hbuf;              // h1 dead after agg_l1

    const int* esrc = ei;
    const int* edst = ei + E;
    const int nspan = (N + 7) >> 3;
    const int nchunk = (E + CHUNK - 1) / CHUNK;

    hipMemsetAsync(degr, 0, (size_t)8 * NPAD * 4, stream);
    hipMemsetAsync(bucketcur, 0, 8 * 4, stream);

    const int gblk = (N + 127) / 128;

    // ---- Mega: layer-1 GEMM || edge bucketing (ballot-based, XCD-local deg) ----
    gemm1_bucket<<<gblk + nchunk, dim3(16, 32), 0, stream>>>(
        x, W1, as1, ad1, hbuf, als, ald, N, gblk,
        esrc, edst, degr, bucketcur, ebuf, E, nspan, nchunk);

    // ---- CSR offsets (sum replicas + self-loop in scan1) ----
    int n1 = N + 1;
    int nb = (n1 + SB - 1) / SB;
    scan1<<<nb, SB, 0, stream>>>(degr, off, bsums, n1, N);
    scan2<<<1, SB, 0, stream>>>(bsums, nb);
    scan3<<<nb, SB, 0, stream>>>(off, cursor, bsums, n1, N);

    // ---- Pass B: XCD-partitioned scatter from buckets ----
    {
        const int spb = 64;
        scatter_b<<<8 * spb, 256, 0, stream>>>(ebuf, bucketcur, cursor, csr, N, nspan, spb);
    }

    // ---- Layer 1 aggregation (edge-group layout) ----
    gat_agg_l1<<<(N * 64 + 255) / 256, 256, 0, stream>>>(
        hbuf, als, ald, b1, off, csr, a1, N);

    // ---- Layer 2: GEMM (fp16 A) + aggregation (edge-group, fused l3 head) ----
    gemm_fused_h<64, 4, 2><<<gblk, dim3(16, 32), 0, stream>>>(
        a1, W2, as2, ad2, h2, als, ald, N);
    gat_agg_l2<<<(N * 64 + 255) / 256, 256, 0, stream>>>(
        h2, als, ald, b2, off, csr, W3, as3, ad3, hs, ald3, N);

    // ---- Layer 3: aggregation of packed scalar feature ----
    gat_agg1<<<(N + 255) / 256, 256, 0, stream>>>(hs, ald3, b3, off, csr, out, N);
}

// Round 19
// 180.848 us; speedup vs baseline: 1.0104x; 1.0104x over previous
//
#include <hip/hip_runtime.h>
#include <hip/hip_fp16.h>
#include <math.h>

#define F_IN 128
constexpr int SB = 256;
constexpr float LOG2E = 1.4426950408889634f;
constexpr int CAP = 131072;   // per-bucket edge capacity
constexpr int CHUNK = 2048;   // edges per bucketing block
constexpr int NPAD = 50176;   // per-replica deg stride (>= N+1, 256B-aligned)

// scan1: exclusive scan input = sum of 8 XCD-local deg replicas (+1 self-loop)
__global__ void scan1(const int* __restrict__ degr, int* __restrict__ out,
                      int* __restrict__ bsums, int n, int selfN) {
    __shared__ int sm[SB];
    int i = blockIdx.x * SB + threadIdx.x;
    int v = 0;
    if (i < n) {
#pragma unroll
        for (int r = 0; r < 8; ++r) v += degr[r * NPAD + i];
        if (i < selfN) v += 1;
    }
    sm[threadIdx.x] = v;
    __syncthreads();
    for (int d = 1; d < SB; d <<= 1) {
        int t = (threadIdx.x >= d) ? sm[threadIdx.x - d] : 0;
        __syncthreads();
        sm[threadIdx.x] += t;
        __syncthreads();
    }
    if (i < n) out[i] = sm[threadIdx.x] - v;
    if (threadIdx.x == SB - 1) bsums[blockIdx.x] = sm[SB - 1];
}

__global__ void scan2(int* __restrict__ bsums, int nb) {
    __shared__ int sm[SB];
    int v = (threadIdx.x < nb) ? bsums[threadIdx.x] : 0;
    sm[threadIdx.x] = v;
    __syncthreads();
    for (int d = 1; d < SB; d <<= 1) {
        int t = (threadIdx.x >= d) ? sm[threadIdx.x - d] : 0;
        __syncthreads();
        sm[threadIdx.x] += t;
        __syncthreads();
    }
    if (threadIdx.x < nb) bsums[threadIdx.x] = sm[threadIdx.x] - v;
}

__global__ void scan3(int* __restrict__ off, int* __restrict__ cursor,
                      const int* __restrict__ bsums, int n, int ncur) {
    int i = blockIdx.x * SB + threadIdx.x;
    if (i < n) {
        int v = off[i] + bsums[blockIdx.x];
        off[i] = v;
        if (i < ncur) cursor[i] = v;
    }
}

// GEMM body, 8x{8|4} micro-tile, block (16,16)=256 threads. LDS bytes/FMA = 1.0
// (was 1.5 at 4x8 -> LDS-BW capped). A float or __half; smem passed in.
// fp16 C; fp32 logit epilogue PRE-SCALED by log2e.
template <int BN, int TN, int HEADS, typename AT>
__device__ __forceinline__ void gemm_dev(
    const AT* __restrict__ A, const float* __restrict__ B,
    const float* __restrict__ asrc, const float* __restrict__ adst,
    __half* __restrict__ C, float* __restrict__ als, float* __restrict__ ald,
    int M, int bid, char* smem) {
    constexpr int BM = 128, BK = 16, TM = 8, K = 128;
    float (*As)[BM + 4] = (float (*)[BM + 4])smem;
    float (*Bs)[BN] = (float (*)[BN])(smem + (size_t)BK * (BM + 4) * 4);
    const int tx = threadIdx.x, ty = threadIdx.y;   // 16 x 16
    const int tid = ty * 16 + tx;
    const int row0 = bid * BM;
    const int i0 = ty * TM;
    const int j0a = tx * 4;
    const int j0b = 64 + tx * 4;

    float acc[TM][TN];
#pragma unroll
    for (int m = 0; m < TM; ++m)
#pragma unroll
        for (int n = 0; n < TN; ++n) acc[m][n] = 0.f;

    // A staging: 128 rows x BK floats; each thread 8 floats (row tid>>1, k-off (tid&1)*8)
    const int ar = tid >> 1;
    const int ak = (tid & 1) * 8;
    int arow = row0 + ar;
    if (arow >= M) arow = M - 1;
    const AT* Aptr = A + (size_t)arow * K + ak;
    // B staging: row bk = tid>>4; BN==128: cols (tid&15)*8 (2 float4); BN==64: (tid&15)*4
    const int bk = tid >> 4;
    const int bc = (BN == 128) ? ((tid & 15) * 8) : ((tid & 15) * 4);

    for (int kc = 0; kc < K; kc += BK) {
        float av[8];
        if constexpr (sizeof(AT) == 4) {
            float4 a0 = *(const float4*)(Aptr + kc);
            float4 a1 = *(const float4*)(Aptr + kc + 4);
            av[0] = a0.x; av[1] = a0.y; av[2] = a0.z; av[3] = a0.w;
            av[4] = a1.x; av[5] = a1.y; av[6] = a1.z; av[7] = a1.w;
        } else {
            uint4 raw = *(const uint4*)(Aptr + kc);
            const __half2* hh = (const __half2*)&raw;
#pragma unroll
            for (int j = 0; j < 4; ++j) {
                float2 f = __half22float2(hh[j]);
                av[2 * j] = f.x;
                av[2 * j + 1] = f.y;
            }
        }
        float4 bv0, bv1;
        bv0 = *(const float4*)(B + (size_t)(kc + bk) * BN + bc);
        if constexpr (BN == 128) bv1 = *(const float4*)(B + (size_t)(kc + bk) * BN + bc + 4);
        __syncthreads();
#pragma unroll
        for (int j = 0; j < 8; ++j) As[ak + j][ar] = av[j];
        *(float4*)&Bs[bk][bc] = bv0;
        if constexpr (BN == 128) *(float4*)&Bs[bk][bc + 4] = bv1;
        __syncthreads();
#pragma unroll
        for (int kk = 0; kk < BK; ++kk) {
            float4 a4a = *(const float4*)&As[kk][i0];
            float4 a4b = *(const float4*)&As[kk][i0 + 4];
            float arr[TM] = {a4a.x, a4a.y, a4a.z, a4a.w, a4b.x, a4b.y, a4b.z, a4b.w};
            float br[TN];
            float4 b0 = *(const float4*)&Bs[kk][j0a];
            br[0] = b0.x; br[1] = b0.y; br[2] = b0.z; br[3] = b0.w;
            if constexpr (TN == 8) {
                float4 b1 = *(const float4*)&Bs[kk][j0b];
                br[4] = b1.x; br[5] = b1.y; br[6] = b1.z; br[7] = b1.w;
            }
#pragma unroll
            for (int m = 0; m < TM; ++m)
#pragma unroll
                for (int n = 0; n < TN; ++n) acc[m][n] += arr[m] * br[n];
        }
    }

#pragma unroll
    for (int m = 0; m < TM; ++m) {
        int row = row0 + i0 + m;
        bool ok = row < M;
        if constexpr (TN == 8) {
            if (ok) {
                alignas(8) __half2 pa[2], pb[2];
#pragma unroll
                for (int n2 = 0; n2 < 2; ++n2) {
                    pa[n2] = __floats2half2_rn(acc[m][2 * n2], acc[m][2 * n2 + 1]);
                    pb[n2] = __floats2half2_rn(acc[m][4 + 2 * n2], acc[m][5 + 2 * n2]);
                }
                *(uint2*)&C[(size_t)row * BN + j0a] = *(uint2*)pa;
                *(uint2*)&C[(size_t)row * BN + j0b] = *(uint2*)pb;
            }
            float psA = 0.f, pdA = 0.f, psB = 0.f, pdB = 0.f;
#pragma unroll
            for (int n = 0; n < 4; ++n) {
                psA += acc[m][n] * asrc[j0a + n];
                pdA += acc[m][n] * adst[j0a + n];
                psB += acc[m][n + 4] * asrc[j0b + n];
                pdB += acc[m][n + 4] * adst[j0b + n];
            }
#pragma unroll
            for (int msk = 1; msk < 8; msk <<= 1) {
                psA += __shfl_xor(psA, msk, 64);
                pdA += __shfl_xor(pdA, msk, 64);
                psB += __shfl_xor(psB, msk, 64);
                pdB += __shfl_xor(pdB, msk, 64);
            }
            if (ok && (tx & 7) == 0) {
                int hA = tx >> 3;
                als[row * HEADS + hA] = psA * LOG2E;
                ald[row * HEADS + hA] = pdA * LOG2E;
                als[row * HEADS + 2 + hA] = psB * LOG2E;
                ald[row * HEADS + 2 + hA] = pdB * LOG2E;
            }
        } else {
            if (ok) {
                alignas(8) __half2 ph[2];
#pragma unroll
                for (int n2 = 0; n2 < 2; ++n2)
                    ph[n2] = __floats2half2_rn(acc[m][2 * n2], acc[m][2 * n2 + 1]);
                *(uint2*)&C[(size_t)row * BN + j0a] = *(uint2*)ph;
            }
            float ps = 0.f, pd = 0.f;
#pragma unroll
            for (int n = 0; n < TN; ++n) {
                ps += acc[m][n] * asrc[j0a + n];
                pd += acc[m][n] * adst[j0a + n];
            }
#pragma unroll
            for (int msk = 1; msk < 8; msk <<= 1) {
                ps += __shfl_xor(ps, msk, 64);
                pd += __shfl_xor(pd, msk, 64);
            }
            if (ok && (tx & 7) == 0) {
                int h0 = tx >> 3;
                als[row * HEADS + h0] = ps * LOG2E;
                ald[row * HEADS + h0] = pd * LOG2E;
            }
        }
    }
}

// Mega-kernel: blocks [0,gblk) = layer-1 GEMM. Blocks [gblk,...) = bucketing
// (256 threads, 8 edges/thread): LDS histogram (plain atomics, r17-proven),
// reserve contiguous chunks (8 global atomics/block), flush coalesced.
__global__ __launch_bounds__(256) void gemm1_bucket(
    const float* __restrict__ A, const float* __restrict__ B,
    const float* __restrict__ asrc, const float* __restrict__ adst,
    __half* __restrict__ C, float* __restrict__ als, float* __restrict__ ald,
    int M, int gblk,
    const int* __restrict__ src, const int* __restrict__ dst,
    int* __restrict__ degr, int* __restrict__ bucketcur,
    int2* __restrict__ ebuf, int E, int nspan, int nchunk) {
    __shared__ __align__(16) char smem[16768];
    if ((int)blockIdx.x < gblk) {
        gemm_dev<128, 8, 4, float>(A, B, asrc, adst, C, als, ald, M, blockIdx.x, smem);
        return;
    }
    int cid = blockIdx.x - gblk;
    if (cid >= nchunk) return;
    int tid = threadIdx.y * 16 + threadIdx.x;  // 0..255
    int* degrep = degr + (blockIdx.x & 7) * NPAD;
    int2* stage = (int2*)smem;
    int* hist = (int*)(smem + CHUNK * 8);
    int* bbase = hist + 8;
    int* gbase = hist + 16;
    if (tid < 8) hist[tid] = 0;
    __syncthreads();
    int ebase = cid * CHUNK;
    int s[8], d[8], bk[8], slot[8];
#pragma unroll
    for (int k = 0; k < 8; ++k) {
        int e = ebase + k * 256 + tid;
        bool v = e < E;
        s[k] = v ? src[e] : 0;
        d[k] = v ? dst[e] : 0;
        bk[k] = -1;
        if (v) {
            bk[k] = d[k] / nspan;
            slot[k] = atomicAdd(&hist[bk[k]], 1);     // LDS atomic
            atomicAdd(&degrep[d[k]], 1);              // XCD-local replica
        }
    }
    __syncthreads();
    if (tid == 0) {
        int run = 0;
#pragma unroll
        for (int b = 0; b < 8; ++b) { bbase[b] = run; run += hist[b]; }
    }
    if (tid < 8) gbase[tid] = atomicAdd(&bucketcur[tid], hist[tid]);
    __syncthreads();
#pragma unroll
    for (int k = 0; k < 8; ++k)
        if (bk[k] >= 0) stage[bbase[bk[k]] + slot[k]] = make_int2(s[k], d[k]);
    __syncthreads();
    for (int b = 0; b < 8; ++b) {
        int c0 = bbase[b], cN = hist[b];
        size_t g0 = (size_t)b * CAP + gbase[b];
        for (int j = tid; j < cN; j += 256) ebuf[g0 + j] = stage[c0 + j];
    }
}

// Pass B: partition g (= blockIdx&7, XCD-aligned) reads its bucket
// sequentially, scatters src (ushort) into its L2-resident csr slice.
__global__ void scatter_b(const int2* __restrict__ ebuf,
                          const int* __restrict__ bucketcur,
                          int* __restrict__ cursor, unsigned short* __restrict__ csr,
                          int N, int nspan, int spb) {
    int g = blockIdx.x & 7;
    int c = blockIdx.x >> 3;
    int tid = threadIdx.x;
    int cnt = bucketcur[g];
    const int2* eb = ebuf + (size_t)g * CAP;
    int stride = spb * 256;
    for (int i = c * 256 + tid; i < cnt; i += stride) {
        int2 e = eb[i];
        int p = atomicAdd(&cursor[e.y], 1);
        csr[p] = (unsigned short)e.x;
    }
    int r0 = g * nspan, r1 = r0 + nspan;
    if (r1 > N) r1 = N;
    for (int i = r0 + c * 256 + tid; i < r1; i += stride) {
        int p = atomicAdd(&cursor[i], 1);
        csr[p] = (unsigned short)i;
    }
}

// Layer-2 GEMM (standalone, fp16 A)
template <int BN, int TN, int HEADS>
__global__ __launch_bounds__(256) void gemm_fused_h(
    const __half* __restrict__ A, const float* __restrict__ B,
    const float* __restrict__ asrc, const float* __restrict__ adst,
    __half* __restrict__ C, float* __restrict__ als, float* __restrict__ ald,
    int M) {
    __shared__ __align__(16) char smem[16 * 132 * 4 + 16 * BN * 4];
    gemm_dev<BN, TN, HEADS, __half>(A, B, asrc, adst, C, als, ald, M, blockIdx.x, smem);
}

// Layer-1 aggregation, edge-group layout: wave = 1 node; 4 groups x 16 lanes.
__global__ void gat_agg_l1(const __half* __restrict__ h,
                           const float* __restrict__ als, const float* __restrict__ ald,
                           const float* __restrict__ bias,
                           const int* __restrict__ off,
                           const unsigned short* __restrict__ csr,
                           __half* __restrict__ out, int n) {
    int wid = (blockIdx.x * blockDim.x + threadIdx.x) >> 6;
    int lane = threadIdx.x & 63;
    if (wid >= n) return;
    const int g = lane >> 4;
    const int q = lane & 15;
    const int hd = q >> 2;
    float ad = ald[wid * 4 + hd];
    int e0 = off[wid], e1 = off[wid + 1];
    const __half* hq = h + q * 8;

    float acc[8] = {0.f, 0.f, 0.f, 0.f, 0.f, 0.f, 0.f, 0.f};
    float D = 0.f;

    auto LD = [&](int ebase, uint4& h4, float& al) {
        int ee = ebase + g;
        int ie = (ee < e1) ? ee : e1 - 1;
        int s = csr[ie];
        float av = als[s * 4 + hd];
        al = (ee < e1) ? av : -1e30f;
        h4 = *(const uint4*)(hq + (size_t)s * 128);
    };
    auto PROC = [&](const uint4& h4, float al) {
        float lg = al + ad;
        lg = fmaxf(lg, 0.2f * lg);
        float exv = exp2f(lg);
        D += exv;
        const __half2* hh = (const __half2*)&h4;
#pragma unroll
        for (int i = 0; i < 4; ++i) {
            float2 f = __half22float2(hh[i]);
            acc[2 * i] = fmaf(exv, f.x, acc[2 * i]);
            acc[2 * i + 1] = fmaf(exv, f.y, acc[2 * i + 1]);
        }
    };

    uint4 hA, hB;
    float alA, alB;
    LD(e0, hA, alA);
    LD(e0 + 4, hB, alB);
    int e = e0;
    for (; e + 8 < e1; e += 8) {
        uint4 nA, nB;
        float nalA, nalB;
        LD(e + 8, nA, nalA);
        LD(e + 12, nB, nalB);
        PROC(hA, alA);
        PROC(hB, alB);
        hA = nA; alA = nalA;
        hB = nB; alB = nalB;
    }
    PROC(hA, alA);
    PROC(hB, alB);

#pragma unroll
    for (int i = 0; i < 8; ++i) {
        acc[i] += __shfl_xor(acc[i], 16, 64);
        acc[i] += __shfl_xor(acc[i], 32, 64);
    }
    D += __shfl_xor(D, 16, 64);
    D += __shfl_xor(D, 32, 64);

    if (g == 0) {
        float inv = 1.f / D;
        alignas(16) __half2 ph[4];
#pragma unroll
        for (int i = 0; i < 4; ++i) {
            float2 bv = ((const float2*)bias)[q * 4 + i];
            float vx = acc[2 * i] * inv + bv.x;
            float vy = acc[2 * i + 1] * inv + bv.y;
            vx = vx > 0.f ? vx : (__expf(vx) - 1.f);
            vy = vy > 0.f ? vy : (__expf(vy) - 1.f);
            ph[i] = __floats2half2_rn(vx, vy);
        }
        *(uint4*)(out + (size_t)wid * 128 + q * 8) = *(uint4*)ph;
    }
}

// Layer-2 aggregation (C=64): 8 groups x 8 lanes; fused layer-3 head.
__global__ void gat_agg_l2(const __half* __restrict__ h,
                           const float* __restrict__ als, const float* __restrict__ ald,
                           const float* __restrict__ bias,
                           const int* __restrict__ off,
                           const unsigned short* __restrict__ csr,
                           const float* __restrict__ W3, const float* __restrict__ as3,
                           const float* __restrict__ ad3, float2* __restrict__ hs,
                           float* __restrict__ ald3, int n) {
    int wid = (blockIdx.x * blockDim.x + threadIdx.x) >> 6;
    int lane = threadIdx.x & 63;
    if (wid >= n) return;
    const int g = lane >> 3;
    const int q = lane & 7;
    const int hd = q >> 2;
    float ad = ald[wid * 2 + hd];
    int e0 = off[wid], e1 = off[wid + 1];
    const __half* hq = h + q * 8;

    float acc[8] = {0.f, 0.f, 0.f, 0.f, 0.f, 0.f, 0.f, 0.f};
    float D = 0.f;

    auto LD = [&](int ebase, uint4& h4, float& al) {
        int ee = ebase + g;
        int ie = (ee < e1) ? ee : e1 - 1;
        int s = csr[ie];
        float av = als[s * 2 + hd];
        al = (ee < e1) ? av : -1e30f;
        h4 = *(const uint4*)(hq + (size_t)s * 64);
    };
    auto PROC = [&](const uint4& h4, float al) {
        float lg = al + ad;
        lg = fmaxf(lg, 0.2f * lg);
        float exv = exp2f(lg);
        D += exv;
        const __half2* hh = (const __half2*)&h4;
#pragma unroll
        for (int i = 0; i < 4; ++i) {
            float2 f = __half22float2(hh[i]);
            acc[2 * i] = fmaf(exv, f.x, acc[2 * i]);
            acc[2 * i + 1] = fmaf(exv, f.y, acc[2 * i + 1]);
        }
    };

    uint4 hA, hB;
    float alA, alB;
    LD(e0, hA, alA);
    LD(e0 + 8, hB, alB);
    int e = e0;
    for (; e + 16 < e1; e += 16) {
        uint4 nA, nB;
        float nalA, nalB;
        LD(e + 16, nA, nalA);
        LD(e + 24, nB, nalB);
        PROC(hA, alA);
        PROC(hB, alB);
        hA = nA; alA = nalA;
        hB = nB; alB = nalB;
    }
    PROC(hA, alA);
    PROC(hB, alB);

#pragma unroll
    for (int i = 0; i < 8; ++i) {
        acc[i] += __shfl_xor(acc[i], 8, 64);
        acc[i] += __shfl_xor(acc[i], 16, 64);
        acc[i] += __shfl_xor(acc[i], 32, 64);
    }
    D += __shfl_xor(D, 8, 64);
    D += __shfl_xor(D, 16, 64);
    D += __shfl_xor(D, 32, 64);

    float inv = 1.f / D;
    float r = 0.f;
#pragma unroll
    for (int i = 0; i < 8; ++i) {
        float v = acc[i] * inv + bias[q * 8 + i];
        v = v > 0.f ? v : (__expf(v) - 1.f);
        r = fmaf(v, W3[q * 8 + i], r);
    }
#pragma unroll
    for (int msk = 1; msk < 8; msk <<= 1) r += __shfl_xor(r, msk, 64);
    if (lane == 0) {
        hs[wid] = make_float2(r, r * as3[0] * LOG2E);
        ald3[wid] = r * ad3[0] * LOG2E;
    }
}

// Layer-3 aggregation: thread per node, 2-wide pipeline, packed 8B gather.
__global__ void gat_agg1(const float2* __restrict__ hs, const float* __restrict__ ald3,
                         const float* __restrict__ bias,
                         const int* __restrict__ off,
                         const unsigned short* __restrict__ csr,
                         float* __restrict__ out, int n) {
    int i = blockIdx.x * blockDim.x + threadIdx.x;
    if (i >= n) return;
    float ad = ald3[i];
    int e0 = off[i], e1 = off[i + 1];
    float S = 0.f, D = 0.f;
    float2 g[2];
    float valid[2];
#pragma unroll
    for (int p = 0; p < 2; ++p) {
        int ee = e0 + p;
        int ie = (ee < e1) ? ee : e1 - 1;
        int s = csr[ie];
        g[p] = hs[s];
        valid[p] = (ee < e1) ? 0.f : -1e30f;
    }
    int e = e0;
    for (; e + 2 < e1; e += 2) {
#pragma unroll
        for (int p = 0; p < 2; ++p) {
            int ee = e + 2 + p;
            int ie = (ee < e1) ? ee : e1 - 1;
            int s = csr[ie];
            float2 ng = hs[s];
            float nvalid = (ee < e1) ? 0.f : -1e30f;
            float lg = g[p].y + ad + valid[p];
            lg = fmaxf(lg, 0.2f * lg);
            float exv = exp2f(lg);
            D += exv;
            S = fmaf(exv, g[p].x, S);
            g[p] = ng;
            valid[p] = nvalid;
        }
    }
#pragma unroll
    for (int p = 0; p < 2; ++p) {
        float lg = g[p].y + ad + valid[p];
        lg = fmaxf(lg, 0.2f * lg);
        float exv = exp2f(lg);
        D += exv;
        S = fmaf(exv, g[p].x, S);
    }
    out[i] = S / D + bias[0];
}

extern "C" void kernel_launch(void* const* d_in, const int* in_sizes, int n_in,
                              void* d_out, int out_size, void* d_ws, size_t ws_size,
                              hipStream_t stream) {
    const float* x   = (const float*)d_in[0];
    const int*   ei  = (const int*)d_in[1];
    const float* W1  = (const float*)d_in[2];
    const float* as1 = (const float*)d_in[3];
    const float* ad1 = (const float*)d_in[4];
    const float* b1  = (const float*)d_in[5];
    const float* W2  = (const float*)d_in[6];
    const float* as2 = (const float*)d_in[7];
    const float* ad2 = (const float*)d_in[8];
    const float* b2  = (const float*)d_in[9];
    const float* W3  = (const float*)d_in[10];
    const float* as3 = (const float*)d_in[11];
    const float* ad3 = (const float*)d_in[12];
    const float* b3  = (const float*)d_in[13];
    float* out = (float*)d_out;

    const int N = in_sizes[0] / F_IN;  // 50000
    const int E = in_sizes[1] / 2;     // 800000
    const int ET = E + N;

    char* w = (char*)d_ws;
    size_t o = 0;
    auto alloc = [&](size_t bytes) -> void* {
        void* p = w + o;
        o += (bytes + 255) & ~(size_t)255;
        return p;
    };
    __half* hbuf = (__half*)alloc((size_t)N * 128 * 2);  // h1; reused as h2
    __half* a1   = (__half*)alloc((size_t)N * 128 * 2);
    float2* hs   = (float2*)alloc((size_t)N * 8);        // {h3, als3'}
    float* als  = (float*)alloc((size_t)N * 4 * 4);
    float* ald  = (float*)alloc((size_t)N * 4 * 4);
    float* ald3 = (float*)alloc((size_t)N * 4);
    int* degr   = (int*)alloc((size_t)8 * NPAD * 4);     // 8 XCD-local replicas
    int* bucketcur = (int*)alloc(8 * 4);
    int* off    = (int*)alloc((size_t)(N + 1) * 4);
    int* cursor = (int*)alloc((size_t)N * 4);
    int* bsums  = (int*)alloc(1024);
    unsigned short* csr = (unsigned short*)alloc((size_t)ET * 2);
    int2* ebuf  = (int2*)alloc((size_t)8 * CAP * 8);

    __half* h2 = hbuf;              // h1 dead after agg_l1

    const int* esrc = ei;
    const int* edst = ei + E;
    const int nspan = (N + 7) >> 3;
    const int nchunk = (E + CHUNK - 1) / CHUNK;

    hipMemsetAsync(degr, 0, (size_t)8 * NPAD * 4, stream);
    hipMemsetAsync(bucketcur, 0, 8 * 4, stream);

    const int gblk = (N + 127) / 128;

    // ---- Mega: layer-1 GEMM (8x8 tile) || edge bucketing ----
    gemm1_bucket<<<gblk + nchunk, dim3(16, 16), 0, stream>>>(
        x, W1, as1, ad1, hbuf, als, ald, N, gblk,
        esrc, edst, degr, bucketcur, ebuf, E, nspan, nchunk);

    // ---- CSR offsets (sum replicas + self-loop in scan1) ----
    int n1 = N + 1;
    int nb = (n1 + SB - 1) / SB;
    scan1<<<nb, SB, 0, stream>>>(degr, off, bsums, n1, N);
    scan2<<<1, SB, 0, stream>>>(bsums, nb);
    scan3<<<nb, SB, 0, stream>>>(off, cursor, bsums, n1, N);

    // ---- Pass B: XCD-partitioned scatter from buckets ----
    {
        const int spb = 64;
        scatter_b<<<8 * spb, 256, 0, stream>>>(ebuf, bucketcur, cursor, csr, N, nspan, spb);
    }

    // ---- Layer 1 aggregation (edge-group layout) ----
    gat_agg_l1<<<(N * 64 + 255) / 256, 256, 0, stream>>>(
        hbuf, als, ald, b1, off, csr, a1, N);

    // ---- Layer 2: GEMM (8x4 tile, fp16 A) + aggregation (fused l3 head) ----
    gemm_fused_h<64, 4, 2><<<gblk, dim3(16, 16), 0, stream>>>(
        a1, W2, as2, ad2, h2, als, ald, N);
    gat_agg_l2<<<(N * 64 + 255) / 256, 256, 0, stream>>>(
        h2, als, ald, b2, off, csr, W3, as3, ad3, hs, ald3, N);

    // ---- Layer 3: aggregation of packed scalar feature ----
    gat_agg1<<<(N + 255) / 256, 256, 0, stream>>>(hs, ald3, b3, off, csr, out, N);
}

// Round 20
// 176.796 us; speedup vs baseline: 1.0335x; 1.0229x over previous
//
#include <hip/hip_runtime.h>
#include <hip/hip_fp16.h>
#include <math.h>

#define F_IN 128
constexpr int SB = 256;
constexpr float LOG2E = 1.4426950408889634f;
constexpr int CAP = 131072;   // per-bucket edge capacity
constexpr int CHUNK = 2048;   // edges per bucketing block
constexpr int NPAD = 50176;   // per-replica deg stride
constexpr int PK = 136;       // padded K stride for transposed weights (fp16)

typedef _Float16 h8 __attribute__((ext_vector_type(8)));
typedef float f4 __attribute__((ext_vector_type(4)));

// Pre-transpose W1[128x128], W2[128x64] (f32 [k][n]) -> fp16 [n][PK]
__global__ void prep_w(const float* __restrict__ W1, const float* __restrict__ W2,
                       _Float16* __restrict__ w1t, _Float16* __restrict__ w2t) {
    int i = blockIdx.x * 256 + threadIdx.x;
    if (i < 128 * 128) {
        int k = i >> 7, n = i & 127;
        w1t[n * PK + k] = (_Float16)W1[i];
    } else {
        int j = i - 128 * 128;
        if (j < 128 * 64) {
            int k = j >> 6, n = j & 63;
            w2t[n * PK + k] = (_Float16)W2[j];
        }
    }
}

// scan1: exclusive scan input = sum of 8 XCD-local deg replicas (+1 self-loop)
__global__ void scan1(const int* __restrict__ degr, int* __restrict__ out,
                      int* __restrict__ bsums, int n, int selfN) {
    __shared__ int sm[SB];
    int i = blockIdx.x * SB + threadIdx.x;
    int v = 0;
    if (i < n) {
#pragma unroll
        for (int r = 0; r < 8; ++r) v += degr[r * NPAD + i];
        if (i < selfN) v += 1;
    }
    sm[threadIdx.x] = v;
    __syncthreads();
    for (int d = 1; d < SB; d <<= 1) {
        int t = (threadIdx.x >= d) ? sm[threadIdx.x - d] : 0;
        __syncthreads();
        sm[threadIdx.x] += t;
        __syncthreads();
    }
    if (i < n) out[i] = sm[threadIdx.x] - v;
    if (threadIdx.x == SB - 1) bsums[blockIdx.x] = sm[SB - 1];
}

__global__ void scan2(int* __restrict__ bsums, int nb) {
    __shared__ int sm[SB];
    int v = (threadIdx.x < nb) ? bsums[threadIdx.x] : 0;
    sm[threadIdx.x] = v;
    __syncthreads();
    for (int d = 1; d < SB; d <<= 1) {
        int t = (threadIdx.x >= d) ? sm[threadIdx.x - d] : 0;
        __syncthreads();
        sm[threadIdx.x] += t;
        __syncthreads();
    }
    if (threadIdx.x < nb) bsums[threadIdx.x] = sm[threadIdx.x] - v;
}

__global__ void scan3(int* __restrict__ off, int* __restrict__ cursor,
                      const int* __restrict__ bsums, int n, int ncur) {
    int i = blockIdx.x * SB + threadIdx.x;
    if (i < n) {
        int v = off[i] + bsums[blockIdx.x];
        off[i] = v;
        if (i < ncur) cursor[i] = v;
    }
}

// MFMA GEMM: C[M, N=NT*16] = A[M,128] * W (Wt fp16 [n][PK] in LDS).
// 256 thr = 4 waves, BM=64 (16-row strip per wave). mfma_f32_16x16x32_f16.
// C/D layout: col=lane&15, row=(lane>>4)*4+reg. Fused logit epilogue
// (pre-scaled by log2e). A is float (cvt) or _Float16 (direct).
template <int NT, int HEADS, typename AT>
__device__ __forceinline__ void gemm_mfma(
    const AT* __restrict__ A, const _Float16* __restrict__ Wt,
    const float* __restrict__ asrc, const float* __restrict__ adst,
    __half* __restrict__ C, float* __restrict__ als, float* __restrict__ ald,
    int M, int bid, _Float16* lds) {
    constexpr int N = NT * 16;
    const int tid = threadIdx.x;
    constexpr int HW = N * PK;          // halfs to stage
    for (int i = tid * 8; i < HW; i += 256 * 8)
        *(uint4*)&lds[i] = *(const uint4*)&Wt[i];
    __syncthreads();
    const int w = tid >> 6;
    const int lane = tid & 63;
    const int l15 = lane & 15, lg = lane >> 4;
    const int strip = bid * 64 + w * 16;
    int arow = strip + l15;
    if (arow >= M) arow = M - 1;

    f4 acc[NT];
#pragma unroll
    for (int t = 0; t < NT; ++t) acc[t] = (f4){0.f, 0.f, 0.f, 0.f};

#pragma unroll
    for (int c = 0; c < 4; ++c) {
        h8 a;
        if constexpr (sizeof(AT) == 4) {
            const float* ap = (const float*)A + (size_t)arow * 128 + c * 32 + lg * 8;
            float4 a0 = *(const float4*)ap;
            float4 a1 = *(const float4*)(ap + 4);
            a[0] = (_Float16)a0.x; a[1] = (_Float16)a0.y;
            a[2] = (_Float16)a0.z; a[3] = (_Float16)a0.w;
            a[4] = (_Float16)a1.x; a[5] = (_Float16)a1.y;
            a[6] = (_Float16)a1.z; a[7] = (_Float16)a1.w;
        } else {
            a = *(const h8*)((const _Float16*)A + (size_t)arow * 128 + c * 32 + lg * 8);
        }
#pragma unroll
        for (int t = 0; t < NT; ++t) {
            h8 b = *(const h8*)(lds + (t * 16 + l15) * PK + c * 32 + lg * 8);
            acc[t] = __builtin_amdgcn_mfma_f32_16x16x32_f16(a, b, acc[t], 0, 0, 0);
        }
    }

    const int rbase = strip + lg * 4;
#pragma unroll
    for (int r = 0; r < 4; ++r) {
        int orow = rbase + r;
        bool ok = orow < M;
        if (ok) {
#pragma unroll
            for (int t = 0; t < NT; ++t)
                C[(size_t)orow * N + t * 16 + l15] = __float2half(acc[t][r]);
        }
#pragma unroll
        for (int h = 0; h < HEADS; ++h) {
            float ps = acc[2 * h][r] * asrc[32 * h + l15]
                     + acc[2 * h + 1][r] * asrc[32 * h + 16 + l15];
            float pd = acc[2 * h][r] * adst[32 * h + l15]
                     + acc[2 * h + 1][r] * adst[32 * h + 16 + l15];
#pragma unroll
            for (int m = 1; m < 16; m <<= 1) {
                ps += __shfl_xor(ps, m, 64);
                pd += __shfl_xor(pd, m, 64);
            }
            if (ok && l15 == 0) {
                als[orow * HEADS + h] = ps * LOG2E;
                ald[orow * HEADS + h] = pd * LOG2E;
            }
        }
    }
}

// Mega: blocks [0,gblk) = MFMA layer-1 GEMM; rest = bucketing (256 thr,
// 8 edges/thread, LDS histogram, XCD-local deg replicas, coalesced flush).
__global__ __launch_bounds__(256) void gemm1_bucket(
    const float* __restrict__ A, const _Float16* __restrict__ w1t,
    const float* __restrict__ asrc, const float* __restrict__ adst,
    __half* __restrict__ C, float* __restrict__ als, float* __restrict__ ald,
    int M, int gblk,
    const int* __restrict__ src, const int* __restrict__ dst,
    int* __restrict__ degr, int* __restrict__ bucketcur,
    int2* __restrict__ ebuf, int E, int nspan, int nchunk) {
    __shared__ __align__(16) char smem[128 * PK * 2];   // 34816 B
    if ((int)blockIdx.x < gblk) {
        gemm_mfma<8, 4, float>(A, w1t, asrc, adst, C, als, ald, M, blockIdx.x,
                               (_Float16*)smem);
        return;
    }
    int cid = blockIdx.x - gblk;
    if (cid >= nchunk) return;
    int tid = threadIdx.x;
    int* degrep = degr + (blockIdx.x & 7) * NPAD;
    int2* stage = (int2*)smem;
    int* hist = (int*)(smem + CHUNK * 8);
    int* bbase = hist + 8;
    int* gbase = hist + 16;
    if (tid < 8) hist[tid] = 0;
    __syncthreads();
    int ebase = cid * CHUNK;
    int s[8], d[8], bk[8], slot[8];
#pragma unroll
    for (int k = 0; k < 8; ++k) {
        int e = ebase + k * 256 + tid;
        bool v = e < E;
        s[k] = v ? src[e] : 0;
        d[k] = v ? dst[e] : 0;
        bk[k] = -1;
        if (v) {
            bk[k] = d[k] / nspan;
            slot[k] = atomicAdd(&hist[bk[k]], 1);
            atomicAdd(&degrep[d[k]], 1);
        }
    }
    __syncthreads();
    if (tid == 0) {
        int run = 0;
#pragma unroll
        for (int b = 0; b < 8; ++b) { bbase[b] = run; run += hist[b]; }
    }
    if (tid < 8) gbase[tid] = atomicAdd(&bucketcur[tid], hist[tid]);
    __syncthreads();
#pragma unroll
    for (int k = 0; k < 8; ++k)
        if (bk[k] >= 0) stage[bbase[bk[k]] + slot[k]] = make_int2(s[k], d[k]);
    __syncthreads();
    for (int b = 0; b < 8; ++b) {
        int c0 = bbase[b], cN = hist[b];
        size_t g0 = (size_t)b * CAP + gbase[b];
        for (int j = tid; j < cN; j += 256) ebuf[g0 + j] = stage[c0 + j];
    }
}

// Layer-2 MFMA GEMM (fp16 A), standalone.
__global__ __launch_bounds__(256) void gemm2_mfma(
    const _Float16* __restrict__ A, const _Float16* __restrict__ w2t,
    const float* __restrict__ asrc, const float* __restrict__ adst,
    __half* __restrict__ C, float* __restrict__ als, float* __restrict__ ald,
    int M) {
    __shared__ __align__(16) char smem[64 * PK * 2];    // 17408 B
    gemm_mfma<4, 2, _Float16>(A, w2t, asrc, adst, C, als, ald, M, blockIdx.x,
                              (_Float16*)smem);
}

// Pass B: partition g (= blockIdx&7) reads its bucket sequentially,
// scatters src (ushort) into its L2-resident csr slice.
__global__ void scatter_b(const int2* __restrict__ ebuf,
                          const int* __restrict__ bucketcur,
                          int* __restrict__ cursor, unsigned short* __restrict__ csr,
                          int N, int nspan, int spb) {
    int g = blockIdx.x & 7;
    int c = blockIdx.x >> 3;
    int tid = threadIdx.x;
    int cnt = bucketcur[g];
    const int2* eb = ebuf + (size_t)g * CAP;
    int stride = spb * 256;
    for (int i = c * 256 + tid; i < cnt; i += stride) {
        int2 e = eb[i];
        int p = atomicAdd(&cursor[e.y], 1);
        csr[p] = (unsigned short)e.x;
    }
    int r0 = g * nspan, r1 = r0 + nspan;
    if (r1 > N) r1 = N;
    for (int i = r0 + c * 256 + tid; i < r1; i += stride) {
        int p = atomicAdd(&cursor[i], 1);
        csr[p] = (unsigned short)i;
    }
}

// Layer-1 aggregation, edge-group layout: wave = 1 node; 4 groups x 16 lanes.
__global__ void gat_agg_l1(const __half* __restrict__ h,
                           const float* __restrict__ als, const float* __restrict__ ald,
                           const float* __restrict__ bias,
                           const int* __restrict__ off,
                           const unsigned short* __restrict__ csr,
                           __half* __restrict__ out, int n) {
    int wid = (blockIdx.x * blockDim.x + threadIdx.x) >> 6;
    int lane = threadIdx.x & 63;
    if (wid >= n) return;
    const int g = lane >> 4;
    const int q = lane & 15;
    const int hd = q >> 2;
    float ad = ald[wid * 4 + hd];
    int e0 = off[wid], e1 = off[wid + 1];
    const __half* hq = h + q * 8;

    float acc[8] = {0.f, 0.f, 0.f, 0.f, 0.f, 0.f, 0.f, 0.f};
    float D = 0.f;

    auto LD = [&](int ebase, uint4& h4, float& al) {
        int ee = ebase + g;
        int ie = (ee < e1) ? ee : e1 - 1;
        int s = csr[ie];
        float av = als[s * 4 + hd];
        al = (ee < e1) ? av : -1e30f;
        h4 = *(const uint4*)(hq + (size_t)s * 128);
    };
    auto PROC = [&](const uint4& h4, float al) {
        float lg = al + ad;
        lg = fmaxf(lg, 0.2f * lg);
        float exv = exp2f(lg);
        D += exv;
        const __half2* hh = (const __half2*)&h4;
#pragma unroll
        for (int i = 0; i < 4; ++i) {
            float2 f = __half22float2(hh[i]);
            acc[2 * i] = fmaf(exv, f.x, acc[2 * i]);
            acc[2 * i + 1] = fmaf(exv, f.y, acc[2 * i + 1]);
        }
    };

    uint4 hA, hB;
    float alA, alB;
    LD(e0, hA, alA);
    LD(e0 + 4, hB, alB);
    int e = e0;
    for (; e + 8 < e1; e += 8) {
        uint4 nA, nB;
        float nalA, nalB;
        LD(e + 8, nA, nalA);
        LD(e + 12, nB, nalB);
        PROC(hA, alA);
        PROC(hB, alB);
        hA = nA; alA = nalA;
        hB = nB; alB = nalB;
    }
    PROC(hA, alA);
    PROC(hB, alB);

#pragma unroll
    for (int i = 0; i < 8; ++i) {
        acc[i] += __shfl_xor(acc[i], 16, 64);
        acc[i] += __shfl_xor(acc[i], 32, 64);
    }
    D += __shfl_xor(D, 16, 64);
    D += __shfl_xor(D, 32, 64);

    if (g == 0) {
        float inv = 1.f / D;
        alignas(16) __half2 ph[4];
#pragma unroll
        for (int i = 0; i < 4; ++i) {
            float2 bv = ((const float2*)bias)[q * 4 + i];
            float vx = acc[2 * i] * inv + bv.x;
            float vy = acc[2 * i + 1] * inv + bv.y;
            vx = vx > 0.f ? vx : (__expf(vx) - 1.f);
            vy = vy > 0.f ? vy : (__expf(vy) - 1.f);
            ph[i] = __floats2half2_rn(vx, vy);
        }
        *(uint4*)(out + (size_t)wid * 128 + q * 8) = *(uint4*)ph;
    }
}

// Layer-2 aggregation (C=64): 8 groups x 8 lanes; fused layer-3 head.
__global__ void gat_agg_l2(const __half* __restrict__ h,
                           const float* __restrict__ als, const float* __restrict__ ald,
                           const float* __restrict__ bias,
                           const int* __restrict__ off,
                           const unsigned short* __restrict__ csr,
                           const float* __restrict__ W3, const float* __restrict__ as3,
                           const float* __restrict__ ad3, float2* __restrict__ hs,
                           float* __restrict__ ald3, int n) {
    int wid = (blockIdx.x * blockDim.x + threadIdx.x) >> 6;
    int lane = threadIdx.x & 63;
    if (wid >= n) return;
    const int g = lane >> 3;
    const int q = lane & 7;
    const int hd = q >> 2;
    float ad = ald[wid * 2 + hd];
    int e0 = off[wid], e1 = off[wid + 1];
    const __half* hq = h + q * 8;

    float acc[8] = {0.f, 0.f, 0.f, 0.f, 0.f, 0.f, 0.f, 0.f};
    float D = 0.f;

    auto LD = [&](int ebase, uint4& h4, float& al) {
        int ee = ebase + g;
        int ie = (ee < e1) ? ee : e1 - 1;
        int s = csr[ie];
        float av = als[s * 2 + hd];
        al = (ee < e1) ? av : -1e30f;
        h4 = *(const uint4*)(hq + (size_t)s * 64);
    };
    auto PROC = [&](const uint4& h4, float al) {
        float lg = al + ad;
        lg = fmaxf(lg, 0.2f * lg);
        float exv = exp2f(lg);
        D += exv;
        const __half2* hh = (const __half2*)&h4;
#pragma unroll
        for (int i = 0; i < 4; ++i) {
            float2 f = __half22float2(hh[i]);
            acc[2 * i] = fmaf(exv, f.x, acc[2 * i]);
            acc[2 * i + 1] = fmaf(exv, f.y, acc[2 * i + 1]);
        }
    };

    uint4 hA, hB;
    float alA, alB;
    LD(e0, hA, alA);
    LD(e0 + 8, hB, alB);
    int e = e0;
    for (; e + 16 < e1; e += 16) {
        uint4 nA, nB;
        float nalA, nalB;
        LD(e + 16, nA, nalA);
        LD(e + 24, nB, nalB);
        PROC(hA, alA);
        PROC(hB, alB);
        hA = nA; alA = nalA;
        hB = nB; alB = nalB;
    }
    PROC(hA, alA);
    PROC(hB, alB);

#pragma unroll
    for (int i = 0; i < 8; ++i) {
        acc[i] += __shfl_xor(acc[i], 8, 64);
        acc[i] += __shfl_xor(acc[i], 16, 64);
        acc[i] += __shfl_xor(acc[i], 32, 64);
    }
    D += __shfl_xor(D, 8, 64);
    D += __shfl_xor(D, 16, 64);
    D += __shfl_xor(D, 32, 64);

    float inv = 1.f / D;
    float r = 0.f;
#pragma unroll
    for (int i = 0; i < 8; ++i) {
        float v = acc[i] * inv + bias[q * 8 + i];
        v = v > 0.f ? v : (__expf(v) - 1.f);
        r = fmaf(v, W3[q * 8 + i], r);
    }
#pragma unroll
    for (int msk = 1; msk < 8; msk <<= 1) r += __shfl_xor(r, msk, 64);
    if (lane == 0) {
        hs[wid] = make_float2(r, r * as3[0] * LOG2E);
        ald3[wid] = r * ad3[0] * LOG2E;
    }
}

// Layer-3 aggregation: thread per node, 2-wide pipeline, packed 8B gather.
__global__ void gat_agg1(const float2* __restrict__ hs, const float* __restrict__ ald3,
                         const float* __restrict__ bias,
                         const int* __restrict__ off,
                         const unsigned short* __restrict__ csr,
                         float* __restrict__ out, int n) {
    int i = blockIdx.x * blockDim.x + threadIdx.x;
    if (i >= n) return;
    float ad = ald3[i];
    int e0 = off[i], e1 = off[i + 1];
    float S = 0.f, D = 0.f;
    float2 g[2];
    float valid[2];
#pragma unroll
    for (int p = 0; p < 2; ++p) {
        int ee = e0 + p;
        int ie = (ee < e1) ? ee : e1 - 1;
        int s = csr[ie];
        g[p] = hs[s];
        valid[p] = (ee < e1) ? 0.f : -1e30f;
    }
    int e = e0;
    for (; e + 2 < e1; e += 2) {
#pragma unroll
        for (int p = 0; p < 2; ++p) {
            int ee = e + 2 + p;
            int ie = (ee < e1) ? ee : e1 - 1;
            int s = csr[ie];
            float2 ng = hs[s];
            float nvalid = (ee < e1) ? 0.f : -1e30f;
            float lg = g[p].y + ad + valid[p];
            lg = fmaxf(lg, 0.2f * lg);
            float exv = exp2f(lg);
            D += exv;
            S = fmaf(exv, g[p].x, S);
            g[p] = ng;
            valid[p] = nvalid;
        }
    }
#pragma unroll
    for (int p = 0; p < 2; ++p) {
        float lg = g[p].y + ad + valid[p];
        lg = fmaxf(lg, 0.2f * lg);
        float exv = exp2f(lg);
        D += exv;
        S = fmaf(exv, g[p].x, S);
    }
    out[i] = S / D + bias[0];
}

extern "C" void kernel_launch(void* const* d_in, const int* in_sizes, int n_in,
                              void* d_out, int out_size, void* d_ws, size_t ws_size,
                              hipStream_t stream) {
    const float* x   = (const float*)d_in[0];
    const int*   ei  = (const int*)d_in[1];
    const float* W1  = (const float*)d_in[2];
    const float* as1 = (const float*)d_in[3];
    const float* ad1 = (const float*)d_in[4];
    const float* b1  = (const float*)d_in[5];
    const float* W2  = (const float*)d_in[6];
    const float* as2 = (const float*)d_in[7];
    const float* ad2 = (const float*)d_in[8];
    const float* b2  = (const float*)d_in[9];
    const float* W3  = (const float*)d_in[10];
    const float* as3 = (const float*)d_in[11];
    const float* ad3 = (const float*)d_in[12];
    const float* b3  = (const float*)d_in[13];
    float* out = (float*)d_out;

    const int N = in_sizes[0] / F_IN;  // 50000
    const int E = in_sizes[1] / 2;     // 800000
    const int ET = E + N;

    char* w = (char*)d_ws;
    size_t o = 0;
    auto alloc = [&](size_t bytes) -> void* {
        void* p = w + o;
        o += (bytes + 255) & ~(size_t)255;
        return p;
    };
    __half* hbuf = (__half*)alloc((size_t)N * 128 * 2);  // h1; reused as h2
    __half* a1   = (__half*)alloc((size_t)N * 128 * 2);
    float2* hs   = (float2*)alloc((size_t)N * 8);        // {h3, als3'}
    float* als  = (float*)alloc((size_t)N * 4 * 4);
    float* ald  = (float*)alloc((size_t)N * 4 * 4);
    float* ald3 = (float*)alloc((size_t)N * 4);
    int* degr   = (int*)alloc((size_t)8 * NPAD * 4);
    int* bucketcur = (int*)alloc(8 * 4);
    int* off    = (int*)alloc((size_t)(N + 1) * 4);
    int* cursor = (int*)alloc((size_t)N * 4);
    int* bsums  = (int*)alloc(1024);
    unsigned short* csr = (unsigned short*)alloc((size_t)ET * 2);
    _Float16* w1t = (_Float16*)alloc(128 * PK * 2);
    _Float16* w2t = (_Float16*)alloc(64 * PK * 2);
    int2* ebuf  = (int2*)alloc((size_t)8 * CAP * 8);

    __half* h2 = hbuf;              // h1 dead after agg_l1

    const int* esrc = ei;
    const int* edst = ei + E;
    const int nspan = (N + 7) >> 3;
    const int nchunk = (E + CHUNK - 1) / CHUNK;

    hipMemsetAsync(degr, 0, (size_t)8 * NPAD * 4, stream);
    hipMemsetAsync(bucketcur, 0, 8 * 4, stream);

    // ---- weight transpose to fp16 ----
    prep_w<<<(128 * 128 + 128 * 64 + 255) / 256, 256, 0, stream>>>(W1, W2, w1t, w2t);

    const int gblk = (N + 63) / 64;

    // ---- Mega: MFMA layer-1 GEMM || edge bucketing ----
    gemm1_bucket<<<gblk + nchunk, 256, 0, stream>>>(
        x, w1t, as1, ad1, hbuf, als, ald, N, gblk,
        esrc, edst, degr, bucketcur, ebuf, E, nspan, nchunk);

    // ---- CSR offsets ----
    int n1 = N + 1;
    int nb = (n1 + SB - 1) / SB;
    scan1<<<nb, SB, 0, stream>>>(degr, off, bsums, n1, N);
    scan2<<<1, SB, 0, stream>>>(bsums, nb);
    scan3<<<nb, SB, 0, stream>>>(off, cursor, bsums, n1, N);

    // ---- Pass B: XCD-partitioned scatter from buckets ----
    {
        const int spb = 32;
        scatter_b<<<8 * spb, 256, 0, stream>>>(ebuf, bucketcur, cursor, csr, N, nspan, spb);
    }

    // ---- Layer 1 aggregation ----
    gat_agg_l1<<<(N * 64 + 255) / 256, 256, 0, stream>>>(
        hbuf, als, ald, b1, off, csr, a1, N);

    // ---- Layer 2: MFMA GEMM + aggregation (fused l3 head) ----
    gemm2_mfma<<<gblk, 256, 0, stream>>>(
        (const _Float16*)a1, w2t, as2, ad2, h2, als, ald, N);
    gat_agg_l2<<<(N * 64 + 255) / 256, 256, 0, stream>>>(
        h2, als, ald, b2, off, csr, W3, as3, ad3, hs, ald3, N);

    // ---- Layer 3 ----
    gat_agg1<<<(N + 255) / 256, 256, 0, stream>>>(hs, ald3, b3, off, csr, out, N);
}